// Round 17
// baseline (2483.801 us; speedup 1.0000x reference)
//
#include <hip/hip_runtime.h>

#define NB 4
#define NC 256
#define ND 64
#define NN 4096

typedef unsigned short us;
using short8v = __attribute__((ext_vector_type(8))) short;
using f32x4   = __attribute__((ext_vector_type(4))) float;

#define MFMA16 __builtin_amdgcn_mfma_f32_16x16x32_bf16

constexpr size_t SBCN = (size_t)NB * NC * NN;   // 4,194,304
constexpr size_t SBN  = (size_t)NB * NN;        // 16,384

__device__ inline us f2bf(float f) {
  unsigned u = __builtin_bit_cast(unsigned, f);
  u += 0x7fffu + ((u >> 16) & 1u);
  return (us)(u >> 16);
}
__device__ inline float bf2f(us s) {
  unsigned u = (unsigned)s << 16;
  return __builtin_bit_cast(float, u);
}

// ---------------- pos = pos_w @ xyz^T + pos_b ----------------
__global__ __launch_bounds__(256) void pos_kernel(
    const float* __restrict__ xyz, const float* __restrict__ pw,
    const float* __restrict__ pb, float* __restrict__ pos)
{
  int idx = blockIdx.x * 256 + threadIdx.x;      // over B*C*N, n fastest
  int n  = idx & (NN - 1);
  int tc = idx >> 12;
  int o  = tc & (NC - 1);
  int b  = tc >> 8;
  const float* xp = xyz + ((size_t)b * NN + n) * 3;
  pos[idx] = pb[o] + pw[o*3+0]*xp[0] + pw[o*3+1]*xp[1] + pw[o*3+2]*xp[2];
}

// ---------------- generic fused weight-GEMM (fp32 core, 64-o tile) --------
// OUT[b,o,n] = epilogue( sum_c W[o,c] * (H[b,c,n] (+P[b,c,n])) )
// Modes: default fp32 [B,O,N] (+OUT2 copy to out-slice);
//   TRIPLE: 3-way bf16 split of q -> OUT/OUT2/OUT3, layout [B,N,64];
//   VSPLIT: 2-way bf16 split of v -> OUT/OUT2, layout [B,C,N].
template<int O, bool ADD_P, bool HAS_BIAS, bool HAS_BN, bool RELU,
         bool HAS_RES, bool TRIPLE, bool VSPLIT, bool HAS_OUT2>
__global__ __launch_bounds__(256) void wgemm(
    const float* __restrict__ W, const float* __restrict__ H,
    const float* __restrict__ P, const float* __restrict__ bias,
    const float* __restrict__ bng, const float* __restrict__ bnb,
    const float* __restrict__ bnm, const float* __restrict__ bnv,
    const float* __restrict__ RES, float* __restrict__ OUT,
    float* __restrict__ OUT2, float* __restrict__ OUT3,
    float* __restrict__ OUT4)
{
  __shared__ float Wt[16][64];   // [c][o]
  __shared__ float Ht[16][64];   // [c][n]
  const int b  = blockIdx.z;
  const int o0 = blockIdx.y * 64;
  const int n0 = blockIdx.x * 64;
  const int t  = threadIdx.x;
  const int og = t >> 4, ng = t & 15;
  const int lo = t >> 2, lc4 = (t & 3) * 4;
  const int hc = t >> 4, hn4 = (t & 15) * 4;
  float acc[4][4] = {};
  for (int c0 = 0; c0 < NC; c0 += 16) {
    float4 w4 = *(const float4*)&W[(size_t)(o0 + lo) * NC + c0 + lc4];
    float4 h4 = *(const float4*)&H[((size_t)b * NC + c0 + hc) * NN + n0 + hn4];
    if (ADD_P) {
      float4 p4 = *(const float4*)&P[((size_t)b * NC + c0 + hc) * NN + n0 + hn4];
      h4.x += p4.x; h4.y += p4.y; h4.z += p4.z; h4.w += p4.w;
    }
    Wt[lc4+0][lo] = w4.x; Wt[lc4+1][lo] = w4.y;
    Wt[lc4+2][lo] = w4.z; Wt[lc4+3][lo] = w4.w;
    *(float4*)&Ht[hc][hn4] = h4;
    __syncthreads();
    #pragma unroll
    for (int cc = 0; cc < 16; ++cc) {
      float4 wv = *(const float4*)&Wt[cc][og*4];
      float4 hv = *(const float4*)&Ht[cc][ng*4];
      float wa[4] = {wv.x, wv.y, wv.z, wv.w};
      float ha[4] = {hv.x, hv.y, hv.z, hv.w};
      #pragma unroll
      for (int i = 0; i < 4; ++i)
        #pragma unroll
        for (int j = 0; j < 4; ++j)
          acc[i][j] += wa[i] * ha[j];
    }
    __syncthreads();
  }
  float vals[4][4];
  #pragma unroll
  for (int i = 0; i < 4; ++i) {
    const int o = o0 + og * 4 + i;
    float sc = 1.0f, sh = 0.0f;
    if (HAS_BIAS) sh = bias[o];
    if (HAS_BN) {
      float inv = bng[o] * rsqrtf(bnv[o] + 1e-5f);
      sh = sh * inv + (bnb[o] - bnm[o] * inv);
      sc = inv;
    }
    #pragma unroll
    for (int j = 0; j < 4; ++j) {
      float v = acc[i][j] * sc + sh;
      if (RELU) v = fmaxf(v, 0.0f);
      vals[i][j] = v;
    }
    if (HAS_RES) {
      float4 rv = *(const float4*)&RES[((size_t)b * NC + o) * NN + n0 + ng*4];
      vals[i][0] += rv.x; vals[i][1] += rv.y;
      vals[i][2] += rv.z; vals[i][3] += rv.w;
    }
  }
  if (TRIPLE) {
    us* o1 = (us*)OUT;  us* o2 = (us*)OUT2;  us* o3 = (us*)OUT3;
    #pragma unroll
    for (int j = 0; j < 4; ++j) {
      const int n = n0 + ng * 4 + j;
      us s1[4], s2[4], s3[4];
      #pragma unroll
      for (int i = 0; i < 4; ++i) {
        float v = vals[i][j];
        us h1 = f2bf(v); float r = v - bf2f(h1);
        us h2 = f2bf(r); r -= bf2f(h2);
        us h3 = f2bf(r);
        s1[i] = h1; s2[i] = h2; s3[i] = h3;
      }
      const size_t base = ((size_t)b * NN + n) * 64 + og * 4;
      uint2 u;
      u.x = (unsigned)s1[0] | ((unsigned)s1[1] << 16);
      u.y = (unsigned)s1[2] | ((unsigned)s1[3] << 16);
      *(uint2*)&o1[base] = u;
      u.x = (unsigned)s2[0] | ((unsigned)s2[1] << 16);
      u.y = (unsigned)s2[2] | ((unsigned)s2[3] << 16);
      *(uint2*)&o2[base] = u;
      u.x = (unsigned)s3[0] | ((unsigned)s3[1] << 16);
      u.y = (unsigned)s3[2] | ((unsigned)s3[3] << 16);
      *(uint2*)&o3[base] = u;
    }
  } else if (VSPLIT) {
    us* v1p = (us*)OUT; us* v2p = (us*)OUT2;
    #pragma unroll
    for (int i = 0; i < 4; ++i) {
      const int o = o0 + og * 4 + i;
      us s1[4], s2[4];
      #pragma unroll
      for (int j = 0; j < 4; ++j) {
        float v = vals[i][j];
        us h1 = f2bf(v);
        s1[j] = h1;
        s2[j] = f2bf(v - bf2f(h1));
      }
      const size_t base = ((size_t)b * NC + o) * NN + n0 + ng * 4;
      uint2 u;
      u.x = (unsigned)s1[0] | ((unsigned)s1[1] << 16);
      u.y = (unsigned)s1[2] | ((unsigned)s1[3] << 16);
      *(uint2*)&v1p[base] = u;
      u.x = (unsigned)s2[0] | ((unsigned)s2[1] << 16);
      u.y = (unsigned)s2[2] | ((unsigned)s2[3] << 16);
      *(uint2*)&v2p[base] = u;
    }
  } else {
    #pragma unroll
    for (int i = 0; i < 4; ++i) {
      const int o = o0 + og * 4 + i;
      float4 r = {vals[i][0], vals[i][1], vals[i][2], vals[i][3]};
      *(float4*)&OUT[((size_t)b * O + o) * NN + n0 + ng*4] = r;
      if (HAS_OUT2)
        *(float4*)&OUT2[((size_t)b * 4 * NC + o) * NN + n0 + ng*4] = r;
    }
  }
}

// ---------------- rowstats via split-MFMA, m-CHUNKED (partial max/sum) -----
__global__ __launch_bounds__(128, 3) void rowstats_mfma(
    const us* __restrict__ q1, const us* __restrict__ q2,
    const us* __restrict__ q3,
    float* __restrict__ Mp, float* __restrict__ Lp)
{
  __shared__ us qs[3][32][72];
  const int b = blockIdx.y;
  const int n0 = blockIdx.x * 32;
  const int mk = blockIdx.z;
  const int t = threadIdx.x;
  const int w = t >> 6, l = t & 63, lm = l & 15, g = l >> 4;
  const int nrow = n0 + w * 16;
  const us* qp[3] = {q1, q2, q3};
  short8v an[3][2];
  #pragma unroll
  for (int s = 0; s < 3; ++s) {
    const size_t ab = ((size_t)b * NN + nrow + lm) * ND + 8 * g;
    an[s][0] = *(const short8v*)(qp[s] + ab);
    an[s][1] = *(const short8v*)(qp[s] + ab + 32);
  }
  float mrun[4], lrun[4];
  #pragma unroll
  for (int r = 0; r < 4; ++r) { mrun[r] = -1e30f; lrun[r] = 0.f; }

  const int nloc0 = t >> 3, d8 = (t & 7) * 8;
  const int mbeg = mk * (NN / 2), mend = mbeg + NN / 2;
  for (int m0 = mbeg; m0 < mend; m0 += 32) {
    __syncthreads();
    #pragma unroll
    for (int i = 0; i < 6; ++i) {
      const int s = i >> 1, n = (i & 1) * 16 + nloc0;
      *(short8v*)&qs[s][n][d8] =
          *(const short8v*)(qp[s] + ((size_t)b * NN + m0 + n) * ND + d8);
    }
    __syncthreads();
    float e[2][4];
    #pragma unroll
    for (int sub = 0; sub < 2; ++sub) {
      f32x4 eA = {0.f,0.f,0.f,0.f}, eB = {0.f,0.f,0.f,0.f};
      #pragma unroll
      for (int kh = 0; kh < 2; ++kh) {
        short8v b0 = *(const short8v*)&qs[0][sub*16+lm][kh*32+8*g];
        short8v b1 = *(const short8v*)&qs[1][sub*16+lm][kh*32+8*g];
        short8v b2 = *(const short8v*)&qs[2][sub*16+lm][kh*32+8*g];
        eA = MFMA16(an[0][kh], b0, eA, 0,0,0);
        eA = MFMA16(an[0][kh], b1, eA, 0,0,0);
        eA = MFMA16(an[0][kh], b2, eA, 0,0,0);
        eB = MFMA16(an[1][kh], b0, eB, 0,0,0);
        eB = MFMA16(an[2][kh], b0, eB, 0,0,0);
        eB = MFMA16(an[1][kh], b1, eB, 0,0,0);
      }
      f32x4 ee = eA + eB;
      #pragma unroll
      for (int r = 0; r < 4; ++r) e[sub][r] = ee[r];
    }
    #pragma unroll
    for (int r = 0; r < 4; ++r) {
      float mx = fmaxf(e[0][r], e[1][r]);
      float p = __expf(e[0][r] - mx) + __expf(e[1][r] - mx);
      float d = mx - mrun[r];
      if (d > 8.f) { lrun[r] = lrun[r] * __expf(-d) + p; mrun[r] = mx; }
      else          lrun[r] += p * __expf(d);
    }
  }
  #pragma unroll
  for (int r = 0; r < 4; ++r) {
    float m = mrun[r], s = lrun[r];
    #pragma unroll
    for (int off = 1; off < 16; off <<= 1) {
      float om = __shfl_xor(m, off);
      float os = __shfl_xor(s, off);
      float nm = fmaxf(m, om);
      s = s * __expf(m - nm) + os * __expf(om - nm);
      m = nm;
    }
    if (lm == 0) {
      Mp[(size_t)mk * SBN + (size_t)b * NN + nrow + 4 * g + r] = m;
      Lp[(size_t)mk * SBN + (size_t)b * NN + nrow + 4 * g + r] = s;
    }
  }
}

// ---- merge 2 m-chunk stat partials: M = max, L = sum(l_k exp(M_k - M)) ----
__global__ __launch_bounds__(256) void statmerge(
    const float* __restrict__ Mp, const float* __restrict__ Lp,
    float* __restrict__ Mr, float* __restrict__ Lr)
{
  const int i = blockIdx.x * 256 + threadIdx.x;   // over SBN
  float m0 = Mp[i], m1 = Mp[SBN + i];
  float l0 = Lp[i], l1 = Lp[SBN + i];
  float M = fmaxf(m0, m1);
  float L = l0 * __expf(m0 - M) + l1 * __expf(m1 - M);
  Mr[i] = M;
  Lr[i] = 1.0f / L;
}

// ------- fused attention: merged-C + c-split waves, nk=4 (4 blocks/CU) -----
// Each block: m-tile 64, ALL C=256, n-chunk NN/4. Energy once per (n,m).
// Wave w: energy rows [w*16,w*16+16); PV c-quarter [w*64, w*64+64).
__global__ __launch_bounds__(256, 4) void fusedatt_mfma(
    const us* __restrict__ q1, const us* __restrict__ q2,
    const us* __restrict__ q3,
    const us* __restrict__ v1, const us* __restrict__ v2,
    const float* __restrict__ Mr, const float* __restrict__ Lr,
    float* __restrict__ xr, float* __restrict__ csb)
{
  __shared__ us qs[2][3][32][72];            // double-buffered q (27.6KB)
  __shared__ us att1[64][40];                // att hi split [m][n]
  __shared__ us att2[64][40];                // att lo split [m][n]
  const int b  = blockIdx.y;
  const int m0 = blockIdx.x * 64;
  const int nk = blockIdx.z;                 // 0..3
  const int t  = threadIdx.x;
  const int w  = t >> 6, l = t & 63, lm = l & 15, g = l >> 4;
  const int mrow = w * 16 + lm;
  const int mg   = m0 + mrow;
  const us* qp[3] = {q1, q2, q3};

  short8v bm[3][2];
  #pragma unroll
  for (int s = 0; s < 3; ++s) {
    const size_t mb = ((size_t)b * NN + mg) * ND + 8 * g;
    bm[s][0] = *(const short8v*)(qp[s] + mb);
    bm[s][1] = *(const short8v*)(qp[s] + mb + 32);
  }
  const float* Mb = Mr + (size_t)b * NN;
  const float* Lb = Lr + (size_t)b * NN;
  const us* vb1 = v1 + ((size_t)b * NC + w * 64 + lm) * NN + 8 * g;
  const us* vb2 = v2 + ((size_t)b * NC + w * 64 + lm) * NN + 8 * g;

  f32x4 acc[4][4];   // [cs][mm]
  const f32x4 fzero = {0.f,0.f,0.f,0.f};
  #pragma unroll
  for (int cs = 0; cs < 4; ++cs)
    #pragma unroll
    for (int mm = 0; mm < 4; ++mm) acc[cs][mm] = fzero;
  float csp = 0.f;

  const int nloc = t >> 3, d8 = (t & 7) * 8;
  const int nbeg = nk * (NN / 4), nend = nbeg + NN / 4;

  // prologue: stage first tile into buffer 0
  #pragma unroll
  for (int i = 0; i < 3; ++i)
    *(short8v*)&qs[0][i][nloc][d8] =
        *(const short8v*)(qp[i] + ((size_t)b * NN + nbeg + nloc) * ND + d8);
  __syncthreads();

  int cur = 0;
  for (int nt = nbeg; nt < nend; nt += 32) {
    short8v nx0, nx1, nx2;
    const bool has_next = (nt + 32) < nend;
    if (has_next) {
      const size_t nb = ((size_t)b * NN + nt + 32 + nloc) * ND + d8;
      nx0 = *(const short8v*)(qp[0] + nb);
      nx1 = *(const short8v*)(qp[1] + nb);
      nx2 = *(const short8v*)(qp[2] + nb);
    }
    // ---- energy from qs[cur]: wave w -> att rows [w*16, w*16+16) ----
    #pragma unroll
    for (int sub = 0; sub < 2; ++sub) {
      f32x4 eA = fzero, eB = fzero;
      #pragma unroll
      for (int kh = 0; kh < 2; ++kh) {
        short8v a0 = *(const short8v*)&qs[cur][0][sub*16+lm][kh*32+8*g];
        short8v a1 = *(const short8v*)&qs[cur][1][sub*16+lm][kh*32+8*g];
        short8v a2 = *(const short8v*)&qs[cur][2][sub*16+lm][kh*32+8*g];
        eA = MFMA16(a0, bm[0][kh], eA, 0,0,0);
        eA = MFMA16(a0, bm[1][kh], eA, 0,0,0);
        eA = MFMA16(a0, bm[2][kh], eA, 0,0,0);
        eB = MFMA16(a1, bm[0][kh], eB, 0,0,0);
        eB = MFMA16(a2, bm[0][kh], eB, 0,0,0);
        eB = MFMA16(a1, bm[1][kh], eB, 0,0,0);
      }
      f32x4 ee = eA + eB;
      // lane's cells: n = nt + sub*16 + 4g + r (A row), m = mg (B col)
      float m4[4], l4[4];
      *(float4*)m4 = *(const float4*)&Mb[nt + sub*16 + 4*g];
      *(float4*)l4 = *(const float4*)&Lb[nt + sub*16 + 4*g];
      us a1r[4], a2r[4];
      #pragma unroll
      for (int r = 0; r < 4; ++r) {
        float p = __expf(ee[r] - m4[r]) * l4[r];
        csp += p;
        us hi = f2bf(p);
        a1r[r] = hi;
        a2r[r] = f2bf(p - bf2f(hi));
      }
      uint2 u;
      u.x = (unsigned)a1r[0] | ((unsigned)a1r[1] << 16);
      u.y = (unsigned)a1r[2] | ((unsigned)a1r[3] << 16);
      *(uint2*)&att1[mrow][sub*16 + 4*g] = u;
      u.x = (unsigned)a2r[0] | ((unsigned)a2r[1] << 16);
      u.y = (unsigned)a2r[2] | ((unsigned)a2r[3] << 16);
      *(uint2*)&att2[mrow][sub*16 + 4*g] = u;
    }
    if (has_next) {
      *(short8v*)&qs[cur ^ 1][0][nloc][d8] = nx0;
      *(short8v*)&qs[cur ^ 1][1][nloc][d8] = nx1;
      *(short8v*)&qs[cur ^ 1][2][nloc][d8] = nx2;
    }
    __syncthreads();   // att visible to all waves; qs[cur^1] staged
    // ---- PV (c-quarter per wave): 4 cs x 4 mm x 3 split pairs ----
    #pragma unroll
    for (int cs = 0; cs < 4; ++cs) {
      short8v av1 = *(const short8v*)(vb1 + (size_t)cs * 16 * NN + nt);
      short8v av2 = *(const short8v*)(vb2 + (size_t)cs * 16 * NN + nt);
      #pragma unroll
      for (int mm = 0; mm < 4; ++mm) {
        short8v batt1 = *(const short8v*)&att1[mm * 16 + lm][8 * g];
        short8v batt2 = *(const short8v*)&att2[mm * 16 + lm][8 * g];
        acc[cs][mm] = MFMA16(av1, batt1, acc[cs][mm], 0,0,0);
        acc[cs][mm] = MFMA16(av2, batt1, acc[cs][mm], 0,0,0);
        acc[cs][mm] = MFMA16(av1, batt2, acc[cs][mm], 0,0,0);
      }
    }
    __syncthreads();   // protect att from next iteration's store
    cur ^= 1;
  }

  // colsum reduce across the 4 g-groups holding the same m
  csp += __shfl_xor(csp, 16);
  csp += __shfl_xor(csp, 32);
  if (l < 16)
    csb[(size_t)nk * SBN + (size_t)b * NN + m0 + w * 16 + l] = csp;

  float* xrp = xr + (size_t)nk * SBCN;
  #pragma unroll
  for (int cs = 0; cs < 4; ++cs) {
    #pragma unroll
    for (int mm = 0; mm < 4; ++mm) {
      #pragma unroll
      for (int r = 0; r < 4; ++r) {
        const int c = w * 64 + cs * 16 + 4 * g + r;
        const int m = m0 + mm * 16 + lm;
        xrp[((size_t)b * NC + c) * NN + m] = acc[cs][mm][r];
      }
    }
  }
}

// ---- combine 4 n-chunk partials: dbuf = h - sum(xr) / (1e-9 + sum(cs)) ----
// dbuf aliases xr chunk 0 (in-place, elementwise safe).
__global__ __launch_bounds__(256) void xr_reduce(
    const float* __restrict__ xr, const float* __restrict__ csb,
    const float* __restrict__ h, float* __restrict__ dbuf)
{
  const int i4 = blockIdx.x * 256 + threadIdx.x;   // over BCN/4
  const int mq = i4 & (NN / 4 - 1);
  const int bc = i4 >> 10;
  const int b  = bc >> 8;
  const size_t off = (size_t)bc * NN + mq * 4;
  float4 a0 = *(const float4*)&xr[off];
  float4 a1 = *(const float4*)&xr[SBCN + off];
  float4 a2 = *(const float4*)&xr[2 * SBCN + off];
  float4 a3 = *(const float4*)&xr[3 * SBCN + off];
  float4 hv = *(const float4*)&h[off];
  const size_t co = (size_t)b * NN + mq * 4;
  float4 c0 = *(const float4*)&csb[co];
  float4 c1 = *(const float4*)&csb[SBN + co];
  float4 c2 = *(const float4*)&csb[2 * SBN + co];
  float4 c3 = *(const float4*)&csb[3 * SBN + co];
  float4 r;
  r.x = hv.x - (a0.x + a1.x + a2.x + a3.x) / (1e-9f + c0.x + c1.x + c2.x + c3.x);
  r.y = hv.y - (a0.y + a1.y + a2.y + a3.y) / (1e-9f + c0.y + c1.y + c2.y + c3.y);
  r.z = hv.z - (a0.z + a1.z + a2.z + a3.z) / (1e-9f + c0.z + c1.z + c2.z + c3.z);
  r.w = hv.w - (a0.w + a1.w + a2.w + a3.w) / (1e-9f + c0.w + c1.w + c2.w + c3.w);
  *(float4*)&dbuf[off] = r;
}

extern "C" void kernel_launch(void* const* d_in, const int* in_sizes, int n_in,
                              void* d_out, int out_size, void* d_ws, size_t ws_size,
                              hipStream_t stream) {
  const float* x      = (const float*)d_in[0];
  const float* xyz    = (const float*)d_in[1];
  const float* pos_w  = (const float*)d_in[2];
  const float* pos_b  = (const float*)d_in[3];
  const float* conv1w = (const float*)d_in[4];
  const float* bn1_g  = (const float*)d_in[5];
  const float* bn1_b  = (const float*)d_in[6];
  const float* bn1_m  = (const float*)d_in[7];
  const float* bn1_v  = (const float*)d_in[8];
  const float* qk_w   = (const float*)d_in[9];
  const float* v_w    = (const float*)d_in[10];
  const float* v_b    = (const float*)d_in[11];
  const float* tr_w   = (const float*)d_in[12];
  const float* tr_b   = (const float*)d_in[13];
  const float* bn_g   = (const float*)d_in[14];
  const float* bn_b   = (const float*)d_in[15];
  const float* bn_m   = (const float*)d_in[16];
  const float* bn_v   = (const float*)d_in[17];
  float* out = (float*)d_out;
  float* ws  = (float*)d_ws;

  const size_t BCN = SBCN;
  const size_t BDN = (size_t)NB * ND * NN;   // 1,048,576
  const size_t BN  = SBN;
  float* pos  = ws;
  float* h    = pos + BCN;
  float* xr   = h   + BCN;          // 4 x BCN partials; xr[0..BCN) doubles as dbuf
  float* Mr   = xr  + 4 * BCN;
  float* Lr   = Mr  + BN;
  float* csb  = Lr  + BN;           // 4 x BN colsum partials
  float* Mp   = csb + 4 * BN;       // 2 x BN stat partials (max)
  float* Lp   = Mp  + 2 * BN;       // 2 x BN stat partials (sum)
  us* qA1 = (us*)(Lp + 2 * BN);
  us* qA2 = qA1 + BDN;
  us* qA3 = qA2 + BDN;
  us* v1  = qA3 + BDN;
  us* v2  = v1  + BCN;

  pos_kernel<<<(NB * NC * NN) / 256, 256, 0, stream>>>(xyz, pos_w, pos_b, pos);

  // conv1 + BN1 + ReLU -> h
  wgemm<256, false, false, true, true, false, false, false, false>
      <<<dim3(NN/64, NC/64, NB), 256, 0, stream>>>(
          conv1w, x, nullptr, nullptr, bn1_g, bn1_b, bn1_m, bn1_v,
          nullptr, h, nullptr, nullptr, nullptr);

  for (int li = 0; li < 4; ++li) {
    const float* qw = qk_w + (size_t)li * ND * NC;
    const float* vw = v_w  + (size_t)li * NC * NC;
    const float* vb = v_b  + (size_t)li * NC;
    const float* tw = tr_w + (size_t)li * NC * NC;
    const float* tb = tr_b + (size_t)li * NC;

    // q = qk_w @ (h + pos) -> 3-way bf16 split [B,N,64]
    wgemm<64, true, false, false, false, false, true, false, false>
        <<<dim3(NN/64, 1, NB), 256, 0, stream>>>(
            qw, h, pos, nullptr, nullptr, nullptr, nullptr, nullptr,
            nullptr, (float*)qA1, (float*)qA2, (float*)qA3, nullptr);

    // v = v_w @ (h + pos) + v_b -> 2-way bf16 split [B,C,N]
    wgemm<256, true, true, false, false, false, false, true, false>
        <<<dim3(NN/64, NC/64, NB), 256, 0, stream>>>(
            vw, h, pos, vb, nullptr, nullptr, nullptr, nullptr,
            nullptr, (float*)v1, (float*)v2, nullptr, nullptr);

    // m-chunked stats + merge
    rowstats_mfma<<<dim3(NN/32, NB, 2), 128, 0, stream>>>(
        qA1, qA2, qA3, Mp, Lp);
    statmerge<<<(unsigned)(BN / 256), 256, 0, stream>>>(Mp, Lp, Mr, Lr);

    // merged-C fusedatt: z = nk (0..3); 1024 blocks = 4 blocks/CU
    fusedatt_mfma<<<dim3(NN/64, NB, 4), 256, 0, stream>>>(
        qA1, qA2, qA3, v1, v2, Mr, Lr, xr, csb);

    xr_reduce<<<(unsigned)(BCN / 1024), 256, 0, stream>>>(xr, csb, h, xr);

    // h = h + relu(bn(tr_w @ dbuf + tr_b)); also write out slice
    wgemm<256, false, true, true, true, true, false, false, true>
        <<<dim3(NN/64, NC/64, NB), 256, 0, stream>>>(
            tw, xr, nullptr, tb, bn_g + li*NC, bn_b + li*NC,
            bn_m + li*NC, bn_v + li*NC,
            h, h, out + (size_t)li * NC * NN, nullptr, nullptr);
  }
}

// Round 18
// 1581.461 us; speedup vs baseline: 1.5706x; 1.5706x over previous
//
#include <hip/hip_runtime.h>

#define NB 4
#define NC 256
#define ND 64
#define NN 4096

typedef unsigned short us;
using short8v = __attribute__((ext_vector_type(8))) short;
using f32x4   = __attribute__((ext_vector_type(4))) float;

#define MFMA16 __builtin_amdgcn_mfma_f32_16x16x32_bf16

constexpr size_t SBCN = (size_t)NB * NC * NN;   // 4,194,304
constexpr size_t SBN  = (size_t)NB * NN;        // 16,384

__device__ inline us f2bf(float f) {
  unsigned u = __builtin_bit_cast(unsigned, f);
  u += 0x7fffu + ((u >> 16) & 1u);
  return (us)(u >> 16);
}
__device__ inline float bf2f(us s) {
  unsigned u = (unsigned)s << 16;
  return __builtin_bit_cast(float, u);
}

// ---------------- pos = pos_w @ xyz^T + pos_b ----------------
__global__ __launch_bounds__(256) void pos_kernel(
    const float* __restrict__ xyz, const float* __restrict__ pw,
    const float* __restrict__ pb, float* __restrict__ pos)
{
  int idx = blockIdx.x * 256 + threadIdx.x;      // over B*C*N, n fastest
  int n  = idx & (NN - 1);
  int tc = idx >> 12;
  int o  = tc & (NC - 1);
  int b  = tc >> 8;
  const float* xp = xyz + ((size_t)b * NN + n) * 3;
  pos[idx] = pb[o] + pw[o*3+0]*xp[0] + pw[o*3+1]*xp[1] + pw[o*3+2]*xp[2];
}

// ---------------- generic fused weight-GEMM (fp32 core, 64-o tile) --------
// OUT[b,o,n] = epilogue( sum_c W[o,c] * (H[b,c,n] (+P[b,c,n])) )
// Modes: default fp32 [B,O,N] (+OUT2 copy to out-slice);
//   TRIPLE: 3-way bf16 split of q -> OUT/OUT2/OUT3, layout [B,N,64];
//   VSPLIT: 2-way bf16 split of v -> OUT/OUT2, layout [B,C,N].
template<int O, bool ADD_P, bool HAS_BIAS, bool HAS_BN, bool RELU,
         bool HAS_RES, bool TRIPLE, bool VSPLIT, bool HAS_OUT2>
__global__ __launch_bounds__(256) void wgemm(
    const float* __restrict__ W, const float* __restrict__ H,
    const float* __restrict__ P, const float* __restrict__ bias,
    const float* __restrict__ bng, const float* __restrict__ bnb,
    const float* __restrict__ bnm, const float* __restrict__ bnv,
    const float* __restrict__ RES, float* __restrict__ OUT,
    float* __restrict__ OUT2, float* __restrict__ OUT3,
    float* __restrict__ OUT4)
{
  __shared__ float Wt[16][64];   // [c][o]
  __shared__ float Ht[16][64];   // [c][n]
  const int b  = blockIdx.z;
  const int o0 = blockIdx.y * 64;
  const int n0 = blockIdx.x * 64;
  const int t  = threadIdx.x;
  const int og = t >> 4, ng = t & 15;
  const int lo = t >> 2, lc4 = (t & 3) * 4;
  const int hc = t >> 4, hn4 = (t & 15) * 4;
  float acc[4][4] = {};
  for (int c0 = 0; c0 < NC; c0 += 16) {
    float4 w4 = *(const float4*)&W[(size_t)(o0 + lo) * NC + c0 + lc4];
    float4 h4 = *(const float4*)&H[((size_t)b * NC + c0 + hc) * NN + n0 + hn4];
    if (ADD_P) {
      float4 p4 = *(const float4*)&P[((size_t)b * NC + c0 + hc) * NN + n0 + hn4];
      h4.x += p4.x; h4.y += p4.y; h4.z += p4.z; h4.w += p4.w;
    }
    Wt[lc4+0][lo] = w4.x; Wt[lc4+1][lo] = w4.y;
    Wt[lc4+2][lo] = w4.z; Wt[lc4+3][lo] = w4.w;
    *(float4*)&Ht[hc][hn4] = h4;
    __syncthreads();
    #pragma unroll
    for (int cc = 0; cc < 16; ++cc) {
      float4 wv = *(const float4*)&Wt[cc][og*4];
      float4 hv = *(const float4*)&Ht[cc][ng*4];
      float wa[4] = {wv.x, wv.y, wv.z, wv.w};
      float ha[4] = {hv.x, hv.y, hv.z, hv.w};
      #pragma unroll
      for (int i = 0; i < 4; ++i)
        #pragma unroll
        for (int j = 0; j < 4; ++j)
          acc[i][j] += wa[i] * ha[j];
    }
    __syncthreads();
  }
  float vals[4][4];
  #pragma unroll
  for (int i = 0; i < 4; ++i) {
    const int o = o0 + og * 4 + i;
    float sc = 1.0f, sh = 0.0f;
    if (HAS_BIAS) sh = bias[o];
    if (HAS_BN) {
      float inv = bng[o] * rsqrtf(bnv[o] + 1e-5f);
      sh = sh * inv + (bnb[o] - bnm[o] * inv);
      sc = inv;
    }
    #pragma unroll
    for (int j = 0; j < 4; ++j) {
      float v = acc[i][j] * sc + sh;
      if (RELU) v = fmaxf(v, 0.0f);
      vals[i][j] = v;
    }
    if (HAS_RES) {
      float4 rv = *(const float4*)&RES[((size_t)b * NC + o) * NN + n0 + ng*4];
      vals[i][0] += rv.x; vals[i][1] += rv.y;
      vals[i][2] += rv.z; vals[i][3] += rv.w;
    }
  }
  if (TRIPLE) {
    us* o1 = (us*)OUT;  us* o2 = (us*)OUT2;  us* o3 = (us*)OUT3;
    #pragma unroll
    for (int j = 0; j < 4; ++j) {
      const int n = n0 + ng * 4 + j;
      us s1[4], s2[4], s3[4];
      #pragma unroll
      for (int i = 0; i < 4; ++i) {
        float v = vals[i][j];
        us h1 = f2bf(v); float r = v - bf2f(h1);
        us h2 = f2bf(r); r -= bf2f(h2);
        us h3 = f2bf(r);
        s1[i] = h1; s2[i] = h2; s3[i] = h3;
      }
      const size_t base = ((size_t)b * NN + n) * 64 + og * 4;
      uint2 u;
      u.x = (unsigned)s1[0] | ((unsigned)s1[1] << 16);
      u.y = (unsigned)s1[2] | ((unsigned)s1[3] << 16);
      *(uint2*)&o1[base] = u;
      u.x = (unsigned)s2[0] | ((unsigned)s2[1] << 16);
      u.y = (unsigned)s2[2] | ((unsigned)s2[3] << 16);
      *(uint2*)&o2[base] = u;
      u.x = (unsigned)s3[0] | ((unsigned)s3[1] << 16);
      u.y = (unsigned)s3[2] | ((unsigned)s3[3] << 16);
      *(uint2*)&o3[base] = u;
    }
  } else if (VSPLIT) {
    us* v1p = (us*)OUT; us* v2p = (us*)OUT2;
    #pragma unroll
    for (int i = 0; i < 4; ++i) {
      const int o = o0 + og * 4 + i;
      us s1[4], s2[4];
      #pragma unroll
      for (int j = 0; j < 4; ++j) {
        float v = vals[i][j];
        us h1 = f2bf(v);
        s1[j] = h1;
        s2[j] = f2bf(v - bf2f(h1));
      }
      const size_t base = ((size_t)b * NC + o) * NN + n0 + ng * 4;
      uint2 u;
      u.x = (unsigned)s1[0] | ((unsigned)s1[1] << 16);
      u.y = (unsigned)s1[2] | ((unsigned)s1[3] << 16);
      *(uint2*)&v1p[base] = u;
      u.x = (unsigned)s2[0] | ((unsigned)s2[1] << 16);
      u.y = (unsigned)s2[2] | ((unsigned)s2[3] << 16);
      *(uint2*)&v2p[base] = u;
    }
  } else {
    #pragma unroll
    for (int i = 0; i < 4; ++i) {
      const int o = o0 + og * 4 + i;
      float4 r = {vals[i][0], vals[i][1], vals[i][2], vals[i][3]};
      *(float4*)&OUT[((size_t)b * O + o) * NN + n0 + ng*4] = r;
      if (HAS_OUT2)
        *(float4*)&OUT2[((size_t)b * 4 * NC + o) * NN + n0 + ng*4] = r;
    }
  }
}

// ---------------- rowstats via split-MFMA, m-CHUNKED (partial max/sum) -----
__global__ __launch_bounds__(128, 3) void rowstats_mfma(
    const us* __restrict__ q1, const us* __restrict__ q2,
    const us* __restrict__ q3,
    float* __restrict__ Mp, float* __restrict__ Lp)
{
  __shared__ us qs[3][32][72];
  const int b = blockIdx.y;
  const int n0 = blockIdx.x * 32;
  const int mk = blockIdx.z;
  const int t = threadIdx.x;
  const int w = t >> 6, l = t & 63, lm = l & 15, g = l >> 4;
  const int nrow = n0 + w * 16;
  const us* qp[3] = {q1, q2, q3};
  short8v an[3][2];
  #pragma unroll
  for (int s = 0; s < 3; ++s) {
    const size_t ab = ((size_t)b * NN + nrow + lm) * ND + 8 * g;
    an[s][0] = *(const short8v*)(qp[s] + ab);
    an[s][1] = *(const short8v*)(qp[s] + ab + 32);
  }
  float mrun[4], lrun[4];
  #pragma unroll
  for (int r = 0; r < 4; ++r) { mrun[r] = -1e30f; lrun[r] = 0.f; }

  const int nloc0 = t >> 3, d8 = (t & 7) * 8;
  const int mbeg = mk * (NN / 2), mend = mbeg + NN / 2;
  for (int m0 = mbeg; m0 < mend; m0 += 32) {
    __syncthreads();
    #pragma unroll
    for (int i = 0; i < 6; ++i) {
      const int s = i >> 1, n = (i & 1) * 16 + nloc0;
      *(short8v*)&qs[s][n][d8] =
          *(const short8v*)(qp[s] + ((size_t)b * NN + m0 + n) * ND + d8);
    }
    __syncthreads();
    float e[2][4];
    #pragma unroll
    for (int sub = 0; sub < 2; ++sub) {
      f32x4 eA = {0.f,0.f,0.f,0.f}, eB = {0.f,0.f,0.f,0.f};
      #pragma unroll
      for (int kh = 0; kh < 2; ++kh) {
        short8v b0 = *(const short8v*)&qs[0][sub*16+lm][kh*32+8*g];
        short8v b1 = *(const short8v*)&qs[1][sub*16+lm][kh*32+8*g];
        short8v b2 = *(const short8v*)&qs[2][sub*16+lm][kh*32+8*g];
        eA = MFMA16(an[0][kh], b0, eA, 0,0,0);
        eA = MFMA16(an[0][kh], b1, eA, 0,0,0);
        eA = MFMA16(an[0][kh], b2, eA, 0,0,0);
        eB = MFMA16(an[1][kh], b0, eB, 0,0,0);
        eB = MFMA16(an[2][kh], b0, eB, 0,0,0);
        eB = MFMA16(an[1][kh], b1, eB, 0,0,0);
      }
      f32x4 ee = eA + eB;
      #pragma unroll
      for (int r = 0; r < 4; ++r) e[sub][r] = ee[r];
    }
    #pragma unroll
    for (int r = 0; r < 4; ++r) {
      float mx = fmaxf(e[0][r], e[1][r]);
      float p = __expf(e[0][r] - mx) + __expf(e[1][r] - mx);
      float d = mx - mrun[r];
      if (d > 8.f) { lrun[r] = lrun[r] * __expf(-d) + p; mrun[r] = mx; }
      else          lrun[r] += p * __expf(d);
    }
  }
  #pragma unroll
  for (int r = 0; r < 4; ++r) {
    float m = mrun[r], s = lrun[r];
    #pragma unroll
    for (int off = 1; off < 16; off <<= 1) {
      float om = __shfl_xor(m, off);
      float os = __shfl_xor(s, off);
      float nm = fmaxf(m, om);
      s = s * __expf(m - nm) + os * __expf(om - nm);
      m = nm;
    }
    if (lm == 0) {
      Mp[(size_t)mk * SBN + (size_t)b * NN + nrow + 4 * g + r] = m;
      Lp[(size_t)mk * SBN + (size_t)b * NN + nrow + 4 * g + r] = s;
    }
  }
}

// ---- merge 2 m-chunk stat partials: M = max, L = sum(l_k exp(M_k - M)) ----
__global__ __launch_bounds__(256) void statmerge(
    const float* __restrict__ Mp, const float* __restrict__ Lp,
    float* __restrict__ Mr, float* __restrict__ Lr)
{
  const int i = blockIdx.x * 256 + threadIdx.x;   // over SBN
  float m0 = Mp[i], m1 = Mp[SBN + i];
  float l0 = Lp[i], l1 = Lp[SBN + i];
  float M = fmaxf(m0, m1);
  float L = l0 * __expf(m0 - M) + l1 * __expf(m1 - M);
  Mr[i] = M;
  Lr[i] = 1.0f / L;
}

// ------- fused attention: merged-C + c-split waves, nk=2 (round-16 best) ---
// Each block: m-tile 64, ALL C=256, n-chunk NN/2. Energy once per (n,m).
// Wave w: energy rows [w*16,w*16+16); PV c-quarter [w*64, w*64+64).
__global__ __launch_bounds__(256, 2) void fusedatt_mfma(
    const us* __restrict__ q1, const us* __restrict__ q2,
    const us* __restrict__ q3,
    const us* __restrict__ v1, const us* __restrict__ v2,
    const float* __restrict__ Mr, const float* __restrict__ Lr,
    float* __restrict__ xr, float* __restrict__ csb)
{
  __shared__ us qs[2][3][32][72];            // double-buffered q (27.6KB)
  __shared__ us att1[64][40];                // att hi split [m][n]
  __shared__ us att2[64][40];                // att lo split [m][n]
  const int b  = blockIdx.y;
  const int m0 = blockIdx.x * 64;
  const int nk = blockIdx.z;                 // 0..1
  const int t  = threadIdx.x;
  const int w  = t >> 6, l = t & 63, lm = l & 15, g = l >> 4;
  const int mrow = w * 16 + lm;
  const int mg   = m0 + mrow;
  const us* qp[3] = {q1, q2, q3};

  short8v bm[3][2];
  #pragma unroll
  for (int s = 0; s < 3; ++s) {
    const size_t mb = ((size_t)b * NN + mg) * ND + 8 * g;
    bm[s][0] = *(const short8v*)(qp[s] + mb);
    bm[s][1] = *(const short8v*)(qp[s] + mb + 32);
  }
  const float* Mb = Mr + (size_t)b * NN;
  const float* Lb = Lr + (size_t)b * NN;
  const us* vb1 = v1 + ((size_t)b * NC + w * 64 + lm) * NN + 8 * g;
  const us* vb2 = v2 + ((size_t)b * NC + w * 64 + lm) * NN + 8 * g;

  f32x4 acc[4][4];   // [cs][mm]
  const f32x4 fzero = {0.f,0.f,0.f,0.f};
  #pragma unroll
  for (int cs = 0; cs < 4; ++cs)
    #pragma unroll
    for (int mm = 0; mm < 4; ++mm) acc[cs][mm] = fzero;
  float csp = 0.f;

  const int nloc = t >> 3, d8 = (t & 7) * 8;
  const int nbeg = nk * (NN / 2), nend = nbeg + NN / 2;

  // prologue: stage first tile into buffer 0
  #pragma unroll
  for (int i = 0; i < 3; ++i)
    *(short8v*)&qs[0][i][nloc][d8] =
        *(const short8v*)(qp[i] + ((size_t)b * NN + nbeg + nloc) * ND + d8);
  __syncthreads();

  int cur = 0;
  for (int nt = nbeg; nt < nend; nt += 32) {
    short8v nx0, nx1, nx2;
    const bool has_next = (nt + 32) < nend;
    if (has_next) {
      const size_t nb = ((size_t)b * NN + nt + 32 + nloc) * ND + d8;
      nx0 = *(const short8v*)(qp[0] + nb);
      nx1 = *(const short8v*)(qp[1] + nb);
      nx2 = *(const short8v*)(qp[2] + nb);
    }
    // ---- energy from qs[cur]: wave w -> att rows [w*16, w*16+16) ----
    #pragma unroll
    for (int sub = 0; sub < 2; ++sub) {
      f32x4 eA = fzero, eB = fzero;
      #pragma unroll
      for (int kh = 0; kh < 2; ++kh) {
        short8v a0 = *(const short8v*)&qs[cur][0][sub*16+lm][kh*32+8*g];
        short8v a1 = *(const short8v*)&qs[cur][1][sub*16+lm][kh*32+8*g];
        short8v a2 = *(const short8v*)&qs[cur][2][sub*16+lm][kh*32+8*g];
        eA = MFMA16(a0, bm[0][kh], eA, 0,0,0);
        eA = MFMA16(a0, bm[1][kh], eA, 0,0,0);
        eA = MFMA16(a0, bm[2][kh], eA, 0,0,0);
        eB = MFMA16(a1, bm[0][kh], eB, 0,0,0);
        eB = MFMA16(a2, bm[0][kh], eB, 0,0,0);
        eB = MFMA16(a1, bm[1][kh], eB, 0,0,0);
      }
      f32x4 ee = eA + eB;
      // lane's cells: n = nt + sub*16 + 4g + r (A row), m = mg (B col)
      float m4[4], l4[4];
      *(float4*)m4 = *(const float4*)&Mb[nt + sub*16 + 4*g];
      *(float4*)l4 = *(const float4*)&Lb[nt + sub*16 + 4*g];
      us a1r[4], a2r[4];
      #pragma unroll
      for (int r = 0; r < 4; ++r) {
        float p = __expf(ee[r] - m4[r]) * l4[r];
        csp += p;
        us hi = f2bf(p);
        a1r[r] = hi;
        a2r[r] = f2bf(p - bf2f(hi));
      }
      uint2 u;
      u.x = (unsigned)a1r[0] | ((unsigned)a1r[1] << 16);
      u.y = (unsigned)a1r[2] | ((unsigned)a1r[3] << 16);
      *(uint2*)&att1[mrow][sub*16 + 4*g] = u;
      u.x = (unsigned)a2r[0] | ((unsigned)a2r[1] << 16);
      u.y = (unsigned)a2r[2] | ((unsigned)a2r[3] << 16);
      *(uint2*)&att2[mrow][sub*16 + 4*g] = u;
    }
    if (has_next) {
      *(short8v*)&qs[cur ^ 1][0][nloc][d8] = nx0;
      *(short8v*)&qs[cur ^ 1][1][nloc][d8] = nx1;
      *(short8v*)&qs[cur ^ 1][2][nloc][d8] = nx2;
    }
    __syncthreads();   // att visible to all waves; qs[cur^1] staged
    // ---- PV (c-quarter per wave): 4 cs x 4 mm x 3 split pairs ----
    #pragma unroll
    for (int cs = 0; cs < 4; ++cs) {
      short8v av1 = *(const short8v*)(vb1 + (size_t)cs * 16 * NN + nt);
      short8v av2 = *(const short8v*)(vb2 + (size_t)cs * 16 * NN + nt);
      #pragma unroll
      for (int mm = 0; mm < 4; ++mm) {
        short8v batt1 = *(const short8v*)&att1[mm * 16 + lm][8 * g];
        short8v batt2 = *(const short8v*)&att2[mm * 16 + lm][8 * g];
        acc[cs][mm] = MFMA16(av1, batt1, acc[cs][mm], 0,0,0);
        acc[cs][mm] = MFMA16(av2, batt1, acc[cs][mm], 0,0,0);
        acc[cs][mm] = MFMA16(av1, batt2, acc[cs][mm], 0,0,0);
      }
    }
    __syncthreads();   // protect att from next iteration's store
    cur ^= 1;
  }

  // colsum reduce across the 4 g-groups holding the same m
  csp += __shfl_xor(csp, 16);
  csp += __shfl_xor(csp, 32);
  if (l < 16)
    csb[(size_t)nk * SBN + (size_t)b * NN + m0 + w * 16 + l] = csp;

  float* xrp = xr + (size_t)nk * SBCN;
  #pragma unroll
  for (int cs = 0; cs < 4; ++cs) {
    #pragma unroll
    for (int mm = 0; mm < 4; ++mm) {
      #pragma unroll
      for (int r = 0; r < 4; ++r) {
        const int c = w * 64 + cs * 16 + 4 * g + r;
        const int m = m0 + mm * 16 + lm;
        xrp[((size_t)b * NC + c) * NN + m] = acc[cs][mm][r];
      }
    }
  }
}

// ---- combine n-chunk partials: dbuf = h - (xr0+xr1) / (1e-9 + cs0+cs1) ----
// dbuf aliases xr chunk 0 (in-place, elementwise safe).
__global__ __launch_bounds__(256) void xr_reduce(
    const float* __restrict__ xr, const float* __restrict__ csb,
    const float* __restrict__ h, float* __restrict__ dbuf)
{
  const int i4 = blockIdx.x * 256 + threadIdx.x;   // over BCN/4
  const int mq = i4 & (NN / 4 - 1);
  const int bc = i4 >> 10;
  const int b  = bc >> 8;
  const size_t off = (size_t)bc * NN + mq * 4;
  float4 a0 = *(const float4*)&xr[off];
  float4 a1 = *(const float4*)&xr[SBCN + off];
  float4 hv = *(const float4*)&h[off];
  const size_t co = (size_t)b * NN + mq * 4;
  float4 c0 = *(const float4*)&csb[co];
  float4 c1 = *(const float4*)&csb[SBN + co];
  float4 r;
  r.x = hv.x - (a0.x + a1.x) / (1e-9f + c0.x + c1.x);
  r.y = hv.y - (a0.y + a1.y) / (1e-9f + c0.y + c1.y);
  r.z = hv.z - (a0.z + a1.z) / (1e-9f + c0.z + c1.z);
  r.w = hv.w - (a0.w + a1.w) / (1e-9f + c0.w + c1.w);
  *(float4*)&dbuf[off] = r;
}

extern "C" void kernel_launch(void* const* d_in, const int* in_sizes, int n_in,
                              void* d_out, int out_size, void* d_ws, size_t ws_size,
                              hipStream_t stream) {
  const float* x      = (const float*)d_in[0];
  const float* xyz    = (const float*)d_in[1];
  const float* pos_w  = (const float*)d_in[2];
  const float* pos_b  = (const float*)d_in[3];
  const float* conv1w = (const float*)d_in[4];
  const float* bn1_g  = (const float*)d_in[5];
  const float* bn1_b  = (const float*)d_in[6];
  const float* bn1_m  = (const float*)d_in[7];
  const float* bn1_v  = (const float*)d_in[8];
  const float* qk_w   = (const float*)d_in[9];
  const float* v_w    = (const float*)d_in[10];
  const float* v_b    = (const float*)d_in[11];
  const float* tr_w   = (const float*)d_in[12];
  const float* tr_b   = (const float*)d_in[13];
  const float* bn_g   = (const float*)d_in[14];
  const float* bn_b   = (const float*)d_in[15];
  const float* bn_m   = (const float*)d_in[16];
  const float* bn_v   = (const float*)d_in[17];
  float* out = (float*)d_out;
  float* ws  = (float*)d_ws;

  const size_t BCN = SBCN;
  const size_t BDN = (size_t)NB * ND * NN;   // 1,048,576
  const size_t BN  = SBN;
  float* pos  = ws;
  float* h    = pos + BCN;
  float* xr   = h   + BCN;          // 2 x BCN partials; xr[0..BCN) doubles as dbuf
  float* Mr   = xr  + 2 * BCN;
  float* Lr   = Mr  + BN;
  float* csb  = Lr  + BN;           // 2 x BN colsum partials
  float* Mp   = csb + 2 * BN;       // 2 x BN stat partials (max)
  float* Lp   = Mp  + 2 * BN;       // 2 x BN stat partials (sum)
  us* qA1 = (us*)(Lp + 2 * BN);
  us* qA2 = qA1 + BDN;
  us* qA3 = qA2 + BDN;
  us* v1  = qA3 + BDN;
  us* v2  = v1  + BCN;

  pos_kernel<<<(NB * NC * NN) / 256, 256, 0, stream>>>(xyz, pos_w, pos_b, pos);

  // conv1 + BN1 + ReLU -> h
  wgemm<256, false, false, true, true, false, false, false, false>
      <<<dim3(NN/64, NC/64, NB), 256, 0, stream>>>(
          conv1w, x, nullptr, nullptr, bn1_g, bn1_b, bn1_m, bn1_v,
          nullptr, h, nullptr, nullptr, nullptr);

  for (int li = 0; li < 4; ++li) {
    const float* qw = qk_w + (size_t)li * ND * NC;
    const float* vw = v_w  + (size_t)li * NC * NC;
    const float* vb = v_b  + (size_t)li * NC;
    const float* tw = tr_w + (size_t)li * NC * NC;
    const float* tb = tr_b + (size_t)li * NC;

    // q = qk_w @ (h + pos) -> 3-way bf16 split [B,N,64]
    wgemm<64, true, false, false, false, false, true, false, false>
        <<<dim3(NN/64, 1, NB), 256, 0, stream>>>(
            qw, h, pos, nullptr, nullptr, nullptr, nullptr, nullptr,
            nullptr, (float*)qA1, (float*)qA2, (float*)qA3, nullptr);

    // v = v_w @ (h + pos) + v_b -> 2-way bf16 split [B,C,N]
    wgemm<256, true, true, false, false, false, false, true, false>
        <<<dim3(NN/64, NC/64, NB), 256, 0, stream>>>(
            vw, h, pos, vb, nullptr, nullptr, nullptr, nullptr,
            nullptr, (float*)v1, (float*)v2, nullptr, nullptr);

    // m-chunked stats + merge
    rowstats_mfma<<<dim3(NN/32, NB, 2), 128, 0, stream>>>(
        qA1, qA2, qA3, Mp, Lp);
    statmerge<<<(unsigned)(BN / 256), 256, 0, stream>>>(Mp, Lp, Mr, Lr);

    // merged-C fusedatt: z = nk (0..1); 512 blocks (round-16 proven best)
    fusedatt_mfma<<<dim3(NN/64, NB, 2), 256, 0, stream>>>(
        qA1, qA2, qA3, v1, v2, Mr, Lr, xr, csb);

    xr_reduce<<<(unsigned)(BCN / 1024), 256, 0, stream>>>(xr, csb, h, xr);

    // h = h + relu(bn(tr_w @ dbuf + tr_b)); also write out slice
    wgemm<256, false, true, true, true, true, false, false, true>
        <<<dim3(NN/64, NC/64, NB), 256, 0, stream>>>(
            tw, xr, nullptr, tb, bn_g + li*NC, bn_b + li*NC,
            bn_m + li*NC, bn_v + li*NC,
            h, h, out + (size_t)li * NC * NN, nullptr, nullptr);
  }
}

// Round 20
// 1580.093 us; speedup vs baseline: 1.5719x; 1.0009x over previous
//
#include <hip/hip_runtime.h>

#define NB 4
#define NC 256
#define ND 64
#define NN 4096

typedef unsigned short us;
using short8v = __attribute__((ext_vector_type(8))) short;
using f32x4   = __attribute__((ext_vector_type(4))) float;

#define MFMA16 __builtin_amdgcn_mfma_f32_16x16x32_bf16

constexpr size_t SBCN = (size_t)NB * NC * NN;   // 4,194,304
constexpr size_t SBN  = (size_t)NB * NN;        // 16,384

__device__ inline us f2bf(float f) {
  unsigned u = __builtin_bit_cast(unsigned, f);
  u += 0x7fffu + ((u >> 16) & 1u);
  return (us)(u >> 16);
}
__device__ inline float bf2f(us s) {
  unsigned u = (unsigned)s << 16;
  return __builtin_bit_cast(float, u);
}

// ---------------- pos = pos_w @ xyz^T + pos_b ----------------
__global__ __launch_bounds__(256) void pos_kernel(
    const float* __restrict__ xyz, const float* __restrict__ pw,
    const float* __restrict__ pb, float* __restrict__ pos)
{
  int idx = blockIdx.x * 256 + threadIdx.x;      // over B*C*N, n fastest
  int n  = idx & (NN - 1);
  int tc = idx >> 12;
  int o  = tc & (NC - 1);
  int b  = tc >> 8;
  const float* xp = xyz + ((size_t)b * NN + n) * 3;
  pos[idx] = pb[o] + pw[o*3+0]*xp[0] + pw[o*3+1]*xp[1] + pw[o*3+2]*xp[2];
}

// ---------------- generic fused weight-GEMM (fp32 core, 64-o tile) --------
// OUT[b,o,n] = epilogue( sum_c W[o,c] * (H[b,c,n] (+P[b,c,n])) )
// Modes: default fp32 [B,O,N] (+OUT2 copy to out-slice);
//   TRIPLE: 3-way bf16 split of q -> OUT/OUT2/OUT3, layout [B,N,64];
//   VSPLIT: 2-way bf16 split of v -> OUT/OUT2, layout [B,C,N].
template<int O, bool ADD_P, bool HAS_BIAS, bool HAS_BN, bool RELU,
         bool HAS_RES, bool TRIPLE, bool VSPLIT, bool HAS_OUT2>
__global__ __launch_bounds__(256) void wgemm(
    const float* __restrict__ W, const float* __restrict__ H,
    const float* __restrict__ P, const float* __restrict__ bias,
    const float* __restrict__ bng, const float* __restrict__ bnb,
    const float* __restrict__ bnm, const float* __restrict__ bnv,
    const float* __restrict__ RES, float* __restrict__ OUT,
    float* __restrict__ OUT2, float* __restrict__ OUT3,
    float* __restrict__ OUT4)
{
  __shared__ float Wt[16][64];   // [c][o]
  __shared__ float Ht[16][64];   // [c][n]
  const int b  = blockIdx.z;
  const int o0 = blockIdx.y * 64;
  const int n0 = blockIdx.x * 64;
  const int t  = threadIdx.x;
  const int og = t >> 4, ng = t & 15;
  const int lo = t >> 2, lc4 = (t & 3) * 4;
  const int hc = t >> 4, hn4 = (t & 15) * 4;
  float acc[4][4] = {};
  for (int c0 = 0; c0 < NC; c0 += 16) {
    float4 w4 = *(const float4*)&W[(size_t)(o0 + lo) * NC + c0 + lc4];
    float4 h4 = *(const float4*)&H[((size_t)b * NC + c0 + hc) * NN + n0 + hn4];
    if (ADD_P) {
      float4 p4 = *(const float4*)&P[((size_t)b * NC + c0 + hc) * NN + n0 + hn4];
      h4.x += p4.x; h4.y += p4.y; h4.z += p4.z; h4.w += p4.w;
    }
    Wt[lc4+0][lo] = w4.x; Wt[lc4+1][lo] = w4.y;
    Wt[lc4+2][lo] = w4.z; Wt[lc4+3][lo] = w4.w;
    *(float4*)&Ht[hc][hn4] = h4;
    __syncthreads();
    #pragma unroll
    for (int cc = 0; cc < 16; ++cc) {
      float4 wv = *(const float4*)&Wt[cc][og*4];
      float4 hv = *(const float4*)&Ht[cc][ng*4];
      float wa[4] = {wv.x, wv.y, wv.z, wv.w};
      float ha[4] = {hv.x, hv.y, hv.z, hv.w};
      #pragma unroll
      for (int i = 0; i < 4; ++i)
        #pragma unroll
        for (int j = 0; j < 4; ++j)
          acc[i][j] += wa[i] * ha[j];
    }
    __syncthreads();
  }
  float vals[4][4];
  #pragma unroll
  for (int i = 0; i < 4; ++i) {
    const int o = o0 + og * 4 + i;
    float sc = 1.0f, sh = 0.0f;
    if (HAS_BIAS) sh = bias[o];
    if (HAS_BN) {
      float inv = bng[o] * rsqrtf(bnv[o] + 1e-5f);
      sh = sh * inv + (bnb[o] - bnm[o] * inv);
      sc = inv;
    }
    #pragma unroll
    for (int j = 0; j < 4; ++j) {
      float v = acc[i][j] * sc + sh;
      if (RELU) v = fmaxf(v, 0.0f);
      vals[i][j] = v;
    }
    if (HAS_RES) {
      float4 rv = *(const float4*)&RES[((size_t)b * NC + o) * NN + n0 + ng*4];
      vals[i][0] += rv.x; vals[i][1] += rv.y;
      vals[i][2] += rv.z; vals[i][3] += rv.w;
    }
  }
  if (TRIPLE) {
    us* o1 = (us*)OUT;  us* o2 = (us*)OUT2;  us* o3 = (us*)OUT3;
    #pragma unroll
    for (int j = 0; j < 4; ++j) {
      const int n = n0 + ng * 4 + j;
      us s1[4], s2[4], s3[4];
      #pragma unroll
      for (int i = 0; i < 4; ++i) {
        float v = vals[i][j];
        us h1 = f2bf(v); float r = v - bf2f(h1);
        us h2 = f2bf(r); r -= bf2f(h2);
        us h3 = f2bf(r);
        s1[i] = h1; s2[i] = h2; s3[i] = h3;
      }
      const size_t base = ((size_t)b * NN + n) * 64 + og * 4;
      uint2 u;
      u.x = (unsigned)s1[0] | ((unsigned)s1[1] << 16);
      u.y = (unsigned)s1[2] | ((unsigned)s1[3] << 16);
      *(uint2*)&o1[base] = u;
      u.x = (unsigned)s2[0] | ((unsigned)s2[1] << 16);
      u.y = (unsigned)s2[2] | ((unsigned)s2[3] << 16);
      *(uint2*)&o2[base] = u;
      u.x = (unsigned)s3[0] | ((unsigned)s3[1] << 16);
      u.y = (unsigned)s3[2] | ((unsigned)s3[3] << 16);
      *(uint2*)&o3[base] = u;
    }
  } else if (VSPLIT) {
    us* v1p = (us*)OUT; us* v2p = (us*)OUT2;
    #pragma unroll
    for (int i = 0; i < 4; ++i) {
      const int o = o0 + og * 4 + i;
      us s1[4], s2[4];
      #pragma unroll
      for (int j = 0; j < 4; ++j) {
        float v = vals[i][j];
        us h1 = f2bf(v);
        s1[j] = h1;
        s2[j] = f2bf(v - bf2f(h1));
      }
      const size_t base = ((size_t)b * NC + o) * NN + n0 + ng * 4;
      uint2 u;
      u.x = (unsigned)s1[0] | ((unsigned)s1[1] << 16);
      u.y = (unsigned)s1[2] | ((unsigned)s1[3] << 16);
      *(uint2*)&v1p[base] = u;
      u.x = (unsigned)s2[0] | ((unsigned)s2[1] << 16);
      u.y = (unsigned)s2[2] | ((unsigned)s2[3] << 16);
      *(uint2*)&v2p[base] = u;
    }
  } else {
    #pragma unroll
    for (int i = 0; i < 4; ++i) {
      const int o = o0 + og * 4 + i;
      float4 r = {vals[i][0], vals[i][1], vals[i][2], vals[i][3]};
      *(float4*)&OUT[((size_t)b * O + o) * NN + n0 + ng*4] = r;
      if (HAS_OUT2)
        *(float4*)&OUT2[((size_t)b * 4 * NC + o) * NN + n0 + ng*4] = r;
    }
  }
}

// ---------------- rowstats via split-MFMA, m-CHUNKED (partial max/sum) -----
__global__ __launch_bounds__(128, 3) void rowstats_mfma(
    const us* __restrict__ q1, const us* __restrict__ q2,
    const us* __restrict__ q3,
    float* __restrict__ Mp, float* __restrict__ Lp)
{
  __shared__ us qs[3][32][72];
  const int b = blockIdx.y;
  const int n0 = blockIdx.x * 32;
  const int mk = blockIdx.z;
  const int t = threadIdx.x;
  const int w = t >> 6, l = t & 63, lm = l & 15, g = l >> 4;
  const int nrow = n0 + w * 16;
  const us* qp[3] = {q1, q2, q3};
  short8v an[3][2];
  #pragma unroll
  for (int s = 0; s < 3; ++s) {
    const size_t ab = ((size_t)b * NN + nrow + lm) * ND + 8 * g;
    an[s][0] = *(const short8v*)(qp[s] + ab);
    an[s][1] = *(const short8v*)(qp[s] + ab + 32);
  }
  float mrun[4], lrun[4];
  #pragma unroll
  for (int r = 0; r < 4; ++r) { mrun[r] = -1e30f; lrun[r] = 0.f; }

  const int nloc0 = t >> 3, d8 = (t & 7) * 8;
  const int mbeg = mk * (NN / 2), mend = mbeg + NN / 2;
  for (int m0 = mbeg; m0 < mend; m0 += 32) {
    __syncthreads();
    #pragma unroll
    for (int i = 0; i < 6; ++i) {
      const int s = i >> 1, n = (i & 1) * 16 + nloc0;
      *(short8v*)&qs[s][n][d8] =
          *(const short8v*)(qp[s] + ((size_t)b * NN + m0 + n) * ND + d8);
    }
    __syncthreads();
    float e[2][4];
    #pragma unroll
    for (int sub = 0; sub < 2; ++sub) {
      f32x4 eA = {0.f,0.f,0.f,0.f}, eB = {0.f,0.f,0.f,0.f};
      #pragma unroll
      for (int kh = 0; kh < 2; ++kh) {
        short8v b0 = *(const short8v*)&qs[0][sub*16+lm][kh*32+8*g];
        short8v b1 = *(const short8v*)&qs[1][sub*16+lm][kh*32+8*g];
        short8v b2 = *(const short8v*)&qs[2][sub*16+lm][kh*32+8*g];
        eA = MFMA16(an[0][kh], b0, eA, 0,0,0);
        eA = MFMA16(an[0][kh], b1, eA, 0,0,0);
        eA = MFMA16(an[0][kh], b2, eA, 0,0,0);
        eB = MFMA16(an[1][kh], b0, eB, 0,0,0);
        eB = MFMA16(an[2][kh], b0, eB, 0,0,0);
        eB = MFMA16(an[1][kh], b1, eB, 0,0,0);
      }
      f32x4 ee = eA + eB;
      #pragma unroll
      for (int r = 0; r < 4; ++r) e[sub][r] = ee[r];
    }
    #pragma unroll
    for (int r = 0; r < 4; ++r) {
      float mx = fmaxf(e[0][r], e[1][r]);
      float p = __expf(e[0][r] - mx) + __expf(e[1][r] - mx);
      float d = mx - mrun[r];
      if (d > 8.f) { lrun[r] = lrun[r] * __expf(-d) + p; mrun[r] = mx; }
      else          lrun[r] += p * __expf(d);
    }
  }
  #pragma unroll
  for (int r = 0; r < 4; ++r) {
    float m = mrun[r], s = lrun[r];
    #pragma unroll
    for (int off = 1; off < 16; off <<= 1) {
      float om = __shfl_xor(m, off);
      float os = __shfl_xor(s, off);
      float nm = fmaxf(m, om);
      s = s * __expf(m - nm) + os * __expf(om - nm);
      m = nm;
    }
    if (lm == 0) {
      Mp[(size_t)mk * SBN + (size_t)b * NN + nrow + 4 * g + r] = m;
      Lp[(size_t)mk * SBN + (size_t)b * NN + nrow + 4 * g + r] = s;
    }
  }
}

// ---- merge 2 m-chunk stat partials: M = max, L = sum(l_k exp(M_k - M)) ----
__global__ __launch_bounds__(256) void statmerge(
    const float* __restrict__ Mp, const float* __restrict__ Lp,
    float* __restrict__ Mr, float* __restrict__ Lr)
{
  const int i = blockIdx.x * 256 + threadIdx.x;   // over SBN
  float m0 = Mp[i], m1 = Mp[SBN + i];
  float l0 = Lp[i], l1 = Lp[SBN + i];
  float M = fmaxf(m0, m1);
  float L = l0 * __expf(m0 - M) + l1 * __expf(m1 - M);
  Mr[i] = M;
  Lr[i] = 1.0f / L;
}

// ------- fused attention: merged-C + c-split waves, nk=2 (round-16 best) ---
// Each block: m-tile 64, ALL C=256, n-chunk NN/2. Energy once per (n,m).
// Wave w: energy rows [w*16,w*16+16); PV c-quarter [w*64, w*64+64).
__global__ __launch_bounds__(256, 2) void fusedatt_mfma(
    const us* __restrict__ q1, const us* __restrict__ q2,
    const us* __restrict__ q3,
    const us* __restrict__ v1, const us* __restrict__ v2,
    const float* __restrict__ Mr, const float* __restrict__ Lr,
    float* __restrict__ xr, float* __restrict__ csb)
{
  __shared__ us qs[2][3][32][72];            // double-buffered q (27.6KB)
  __shared__ us att1[64][40];                // att hi split [m][n]
  __shared__ us att2[64][40];                // att lo split [m][n]
  const int b  = blockIdx.y;
  const int m0 = blockIdx.x * 64;
  const int nk = blockIdx.z;                 // 0..1
  const int t  = threadIdx.x;
  const int w  = t >> 6, l = t & 63, lm = l & 15, g = l >> 4;
  const int mrow = w * 16 + lm;
  const int mg   = m0 + mrow;
  const us* qp[3] = {q1, q2, q3};

  short8v bm[3][2];
  #pragma unroll
  for (int s = 0; s < 3; ++s) {
    const size_t mb = ((size_t)b * NN + mg) * ND + 8 * g;
    bm[s][0] = *(const short8v*)(qp[s] + mb);
    bm[s][1] = *(const short8v*)(qp[s] + mb + 32);
  }
  const float* Mb = Mr + (size_t)b * NN;
  const float* Lb = Lr + (size_t)b * NN;
  const us* vb1 = v1 + ((size_t)b * NC + w * 64 + lm) * NN + 8 * g;
  const us* vb2 = v2 + ((size_t)b * NC + w * 64 + lm) * NN + 8 * g;

  f32x4 acc[4][4];   // [cs][mm]
  const f32x4 fzero = {0.f,0.f,0.f,0.f};
  #pragma unroll
  for (int cs = 0; cs < 4; ++cs)
    #pragma unroll
    for (int mm = 0; mm < 4; ++mm) acc[cs][mm] = fzero;
  float csp = 0.f;

  const int nloc = t >> 3, d8 = (t & 7) * 8;
  const int nbeg = nk * (NN / 2), nend = nbeg + NN / 2;

  // prologue: stage first tile into buffer 0
  #pragma unroll
  for (int i = 0; i < 3; ++i)
    *(short8v*)&qs[0][i][nloc][d8] =
        *(const short8v*)(qp[i] + ((size_t)b * NN + nbeg + nloc) * ND + d8);
  __syncthreads();

  int cur = 0;
  for (int nt = nbeg; nt < nend; nt += 32) {
    short8v nx0, nx1, nx2;
    const bool has_next = (nt + 32) < nend;
    if (has_next) {
      const size_t nb = ((size_t)b * NN + nt + 32 + nloc) * ND + d8;
      nx0 = *(const short8v*)(qp[0] + nb);
      nx1 = *(const short8v*)(qp[1] + nb);
      nx2 = *(const short8v*)(qp[2] + nb);
    }
    // ---- energy from qs[cur]: wave w -> att rows [w*16, w*16+16) ----
    #pragma unroll
    for (int sub = 0; sub < 2; ++sub) {
      f32x4 eA = fzero, eB = fzero;
      #pragma unroll
      for (int kh = 0; kh < 2; ++kh) {
        short8v a0 = *(const short8v*)&qs[cur][0][sub*16+lm][kh*32+8*g];
        short8v a1 = *(const short8v*)&qs[cur][1][sub*16+lm][kh*32+8*g];
        short8v a2 = *(const short8v*)&qs[cur][2][sub*16+lm][kh*32+8*g];
        eA = MFMA16(a0, bm[0][kh], eA, 0,0,0);
        eA = MFMA16(a0, bm[1][kh], eA, 0,0,0);
        eA = MFMA16(a0, bm[2][kh], eA, 0,0,0);
        eB = MFMA16(a1, bm[0][kh], eB, 0,0,0);
        eB = MFMA16(a2, bm[0][kh], eB, 0,0,0);
        eB = MFMA16(a1, bm[1][kh], eB, 0,0,0);
      }
      f32x4 ee = eA + eB;
      // lane's cells: n = nt + sub*16 + 4g + r (A row), m = mg (B col)
      float m4[4], l4[4];
      *(float4*)m4 = *(const float4*)&Mb[nt + sub*16 + 4*g];
      *(float4*)l4 = *(const float4*)&Lb[nt + sub*16 + 4*g];
      us a1r[4], a2r[4];
      #pragma unroll
      for (int r = 0; r < 4; ++r) {
        float p = __expf(ee[r] - m4[r]) * l4[r];
        csp += p;
        us hi = f2bf(p);
        a1r[r] = hi;
        a2r[r] = f2bf(p - bf2f(hi));
      }
      uint2 u;
      u.x = (unsigned)a1r[0] | ((unsigned)a1r[1] << 16);
      u.y = (unsigned)a1r[2] | ((unsigned)a1r[3] << 16);
      *(uint2*)&att1[mrow][sub*16 + 4*g] = u;
      u.x = (unsigned)a2r[0] | ((unsigned)a2r[1] << 16);
      u.y = (unsigned)a2r[2] | ((unsigned)a2r[3] << 16);
      *(uint2*)&att2[mrow][sub*16 + 4*g] = u;
    }
    if (has_next) {
      *(short8v*)&qs[cur ^ 1][0][nloc][d8] = nx0;
      *(short8v*)&qs[cur ^ 1][1][nloc][d8] = nx1;
      *(short8v*)&qs[cur ^ 1][2][nloc][d8] = nx2;
    }
    __syncthreads();   // att visible to all waves; qs[cur^1] staged
    // ---- PV (c-quarter per wave): 4 cs x 4 mm x 3 split pairs ----
    #pragma unroll
    for (int cs = 0; cs < 4; ++cs) {
      short8v av1 = *(const short8v*)(vb1 + (size_t)cs * 16 * NN + nt);
      short8v av2 = *(const short8v*)(vb2 + (size_t)cs * 16 * NN + nt);
      #pragma unroll
      for (int mm = 0; mm < 4; ++mm) {
        short8v batt1 = *(const short8v*)&att1[mm * 16 + lm][8 * g];
        short8v batt2 = *(const short8v*)&att2[mm * 16 + lm][8 * g];
        acc[cs][mm] = MFMA16(av1, batt1, acc[cs][mm], 0,0,0);
        acc[cs][mm] = MFMA16(av2, batt1, acc[cs][mm], 0,0,0);
        acc[cs][mm] = MFMA16(av1, batt2, acc[cs][mm], 0,0,0);
      }
    }
    __syncthreads();   // protect att from next iteration's store
    cur ^= 1;
  }

  // colsum reduce across the 4 g-groups holding the same m
  csp += __shfl_xor(csp, 16);
  csp += __shfl_xor(csp, 32);
  if (l < 16)
    csb[(size_t)nk * SBN + (size_t)b * NN + m0 + w * 16 + l] = csp;

  float* xrp = xr + (size_t)nk * SBCN;
  #pragma unroll
  for (int cs = 0; cs < 4; ++cs) {
    #pragma unroll
    for (int mm = 0; mm < 4; ++mm) {
      #pragma unroll
      for (int r = 0; r < 4; ++r) {
        const int c = w * 64 + cs * 16 + 4 * g + r;
        const int m = m0 + mm * 16 + lm;
        xrp[((size_t)b * NC + c) * NN + m] = acc[cs][mm][r];
      }
    }
  }
}

// ---- combine n-chunk partials: dbuf = h - (xr0+xr1) / (1e-9 + cs0+cs1) ----
// dbuf aliases xr chunk 0 (in-place, elementwise safe).
__global__ __launch_bounds__(256) void xr_reduce(
    const float* __restrict__ xr, const float* __restrict__ csb,
    const float* __restrict__ h, float* __restrict__ dbuf)
{
  const int i4 = blockIdx.x * 256 + threadIdx.x;   // over BCN/4
  const int mq = i4 & (NN / 4 - 1);
  const int bc = i4 >> 10;
  const int b  = bc >> 8;
  const size_t off = (size_t)bc * NN + mq * 4;
  float4 a0 = *(const float4*)&xr[off];
  float4 a1 = *(const float4*)&xr[SBCN + off];
  float4 hv = *(const float4*)&h[off];
  const size_t co = (size_t)b * NN + mq * 4;
  float4 c0 = *(const float4*)&csb[co];
  float4 c1 = *(const float4*)&csb[SBN + co];
  float4 r;
  r.x = hv.x - (a0.x + a1.x) / (1e-9f + c0.x + c1.x);
  r.y = hv.y - (a0.y + a1.y) / (1e-9f + c0.y + c1.y);
  r.z = hv.z - (a0.z + a1.z) / (1e-9f + c0.z + c1.z);
  r.w = hv.w - (a0.w + a1.w) / (1e-9f + c0.w + c1.w);
  *(float4*)&dbuf[off] = r;
}

extern "C" void kernel_launch(void* const* d_in, const int* in_sizes, int n_in,
                              void* d_out, int out_size, void* d_ws, size_t ws_size,
                              hipStream_t stream) {
  const float* x      = (const float*)d_in[0];
  const float* xyz    = (const float*)d_in[1];
  const float* pos_w  = (const float*)d_in[2];
  const float* pos_b  = (const float*)d_in[3];
  const float* conv1w = (const float*)d_in[4];
  const float* bn1_g  = (const float*)d_in[5];
  const float* bn1_b  = (const float*)d_in[6];
  const float* bn1_m  = (const float*)d_in[7];
  const float* bn1_v  = (const float*)d_in[8];
  const float* qk_w   = (const float*)d_in[9];
  const float* v_w    = (const float*)d_in[10];
  const float* v_b    = (const float*)d_in[11];
  const float* tr_w   = (const float*)d_in[12];
  const float* tr_b   = (const float*)d_in[13];
  const float* bn_g   = (const float*)d_in[14];
  const float* bn_b   = (const float*)d_in[15];
  const float* bn_m   = (const float*)d_in[16];
  const float* bn_v   = (const float*)d_in[17];
  float* out = (float*)d_out;
  float* ws  = (float*)d_ws;

  const size_t BCN = SBCN;
  const size_t BDN = (size_t)NB * ND * NN;   // 1,048,576
  const size_t BN  = SBN;
  float* pos  = ws;
  float* h    = pos + BCN;
  float* xr   = h   + BCN;          // 2 x BCN partials; xr[0..BCN) doubles as dbuf
  float* Mr   = xr  + 2 * BCN;
  float* Lr   = Mr  + BN;
  float* csb  = Lr  + BN;           // 2 x BN colsum partials
  float* Mp   = csb + 2 * BN;       // 2 x BN stat partials (max)
  float* Lp   = Mp  + 2 * BN;       // 2 x BN stat partials (sum)
  us* qA1 = (us*)(Lp + 2 * BN);
  us* qA2 = qA1 + BDN;
  us* qA3 = qA2 + BDN;
  us* v1  = qA3 + BDN;
  us* v2  = v1  + BCN;

  pos_kernel<<<(NB * NC * NN) / 256, 256, 0, stream>>>(xyz, pos_w, pos_b, pos);

  // conv1 + BN1 + ReLU -> h
  wgemm<256, false, false, true, true, false, false, false, false>
      <<<dim3(NN/64, NC/64, NB), 256, 0, stream>>>(
          conv1w, x, nullptr, nullptr, bn1_g, bn1_b, bn1_m, bn1_v,
          nullptr, h, nullptr, nullptr, nullptr);

  for (int li = 0; li < 4; ++li) {
    const float* qw = qk_w + (size_t)li * ND * NC;
    const float* vw = v_w  + (size_t)li * NC * NC;
    const float* vb = v_b  + (size_t)li * NC;
    const float* tw = tr_w + (size_t)li * NC * NC;
    const float* tb = tr_b + (size_t)li * NC;

    // q = qk_w @ (h + pos) -> 3-way bf16 split [B,N,64]
    wgemm<64, true, false, false, false, false, true, false, false>
        <<<dim3(NN/64, 1, NB), 256, 0, stream>>>(
            qw, h, pos, nullptr, nullptr, nullptr, nullptr, nullptr,
            nullptr, (float*)qA1, (float*)qA2, (float*)qA3, nullptr);

    // v = v_w @ (h + pos) + v_b -> 2-way bf16 split [B,C,N]
    wgemm<256, true, true, false, false, false, false, true, false>
        <<<dim3(NN/64, NC/64, NB), 256, 0, stream>>>(
            vw, h, pos, vb, nullptr, nullptr, nullptr, nullptr,
            nullptr, (float*)v1, (float*)v2, nullptr, nullptr);

    // m-chunked stats + merge
    rowstats_mfma<<<dim3(NN/32, NB, 2), 128, 0, stream>>>(
        qA1, qA2, qA3, Mp, Lp);
    statmerge<<<(unsigned)(BN / 256), 256, 0, stream>>>(Mp, Lp, Mr, Lr);

    // merged-C fusedatt: z = nk (0..1); 512 blocks (round-16 proven best)
    fusedatt_mfma<<<dim3(NN/64, NB, 2), 256, 0, stream>>>(
        qA1, qA2, qA3, v1, v2, Mr, Lr, xr, csb);

    xr_reduce<<<(unsigned)(BCN / 1024), 256, 0, stream>>>(xr, csb, h, xr);

    // h = h + relu(bn(tr_w @ dbuf + tr_b)); also write out slice
    wgemm<256, false, true, true, true, true, false, false, true>
        <<<dim3(NN/64, NC/64, NB), 256, 0, stream>>>(
            tw, xr, nullptr, tb, bn_g + li*NC, bn_b + li*NC,
            bn_m + li*NC, bn_v + li*NC,
            h, h, out + (size_t)li * NC * NN, nullptr, nullptr);
  }
}